// Round 1
// baseline (25.566 us; speedup 1.0000x reference)
//
#include <hip/hip_runtime.h>
#include <math.h>

// EGES: hidden = softmax(W_weights[central]) . {item_emb, side0, mean(side1)}
//       out[b,c] = sigmoid(dot(hidden[b], W_item_out[context[b,c]]))
// B=16384, C=6, D=128. One wave (64 lanes) per row, float2 per lane.

#define B_CONST 16384
#define C_CONST 6
#define D_CONST 128

__global__ __launch_bounds__(256) void eges_kernel(
    const int* __restrict__ central,       // [B]
    const int* __restrict__ side0,         // [B]
    const int* __restrict__ side1,         // [B,5]
    const int* __restrict__ ctx_items,     // [B,C]
    const float* __restrict__ W_item_in,   // [N,D]
    const float* __restrict__ W_item_out,  // [N,D]
    const float* __restrict__ W_weights,   // [N,3]
    const float* __restrict__ W_side0,     // [V0,D]
    const float* __restrict__ W_side1,     // [V1,D]
    float* __restrict__ out,               // [B,C]
    int B)
{
    const int wave = threadIdx.x >> 6;        // 4 waves/block
    const int lane = threadIdx.x & 63;
    const int b = (blockIdx.x << 2) + wave;
    if (b >= B) return;

    const int ci = central[b];

    // softmax over 3 weights (wave-uniform, redundant per lane — cheap)
    const float* wp = &W_weights[(long long)ci * 3];
    float w0 = wp[0], w1 = wp[1], w2 = wp[2];
    float m = fmaxf(w0, fmaxf(w1, w2));
    float e0 = __expf(w0 - m), e1 = __expf(w1 - m), e2 = __expf(w2 - m);
    float inv = 1.0f / (e0 + e1 + e2);
    w0 = e0 * inv; w1 = e1 * inv; w2 = e2 * inv;

    const int d = lane * 2;   // each lane owns 2 consecutive floats of the 128

    float2 item = *(const float2*)&W_item_in[(long long)ci * D_CONST + d];
    float2 s0v  = *(const float2*)&W_side0[(long long)side0[b] * D_CONST + d];

    float sx = 0.f, sy = 0.f;
    #pragma unroll
    for (int j = 0; j < 5; ++j) {
        int i1 = side1[b * 5 + j];
        float2 t = *(const float2*)&W_side1[(long long)i1 * D_CONST + d];
        sx += t.x; sy += t.y;
    }
    sx *= 0.2f; sy *= 0.2f;

    const float hx = w0 * item.x + w1 * s0v.x + w2 * sx;
    const float hy = w0 * item.y + w1 * s0v.y + w2 * sy;

    #pragma unroll
    for (int c = 0; c < C_CONST; ++c) {
        int oi = ctx_items[b * C_CONST + c];
        float2 o = *(const float2*)&W_item_out[(long long)oi * D_CONST + d];
        float p = hx * o.x + hy * o.y;
        // 64-lane butterfly reduction
        #pragma unroll
        for (int off = 32; off >= 1; off >>= 1)
            p += __shfl_xor(p, off, 64);
        if (lane == 0)
            out[b * C_CONST + c] = 1.0f / (1.0f + __expf(-p));
    }
}

extern "C" void kernel_launch(void* const* d_in, const int* in_sizes, int n_in,
                              void* d_out, int out_size, void* d_ws, size_t ws_size,
                              hipStream_t stream) {
    const int*   central    = (const int*)d_in[0];
    const int*   side0      = (const int*)d_in[1];
    const int*   side1      = (const int*)d_in[2];
    const int*   ctx_items  = (const int*)d_in[3];
    const float* W_item_in  = (const float*)d_in[4];
    const float* W_item_out = (const float*)d_in[5];
    const float* W_weights  = (const float*)d_in[6];
    const float* W_side0    = (const float*)d_in[7];
    const float* W_side1    = (const float*)d_in[8];
    float* out = (float*)d_out;

    const int B = in_sizes[0];              // 16384
    const int blocks = (B + 3) / 4;         // 4 rows (waves) per 256-thread block

    eges_kernel<<<blocks, 256, 0, stream>>>(
        central, side0, side1, ctx_items,
        W_item_in, W_item_out, W_weights, W_side0, W_side1,
        out, B);
}

// Round 2
// 22.575 us; speedup vs baseline: 1.1325x; 1.1325x over previous
//
#include <hip/hip_runtime.h>
#include <math.h>

// EGES: hidden = softmax(W_weights[central]) . {item_emb, side0, mean(side1)}
//       out[b,c] = sigmoid(dot(hidden[b], W_item_out[context[b,c]]))
// B=16384, C=6, D=128.
// Layout: one wave handles TWO rows b (lane>>5 picks the row); each half-wave's
// 32 lanes cover one 512B embedding row with float4 loads -> every gather
// instruction moves 1KB. Reduction is a 5-step shfl_xor within the half-wave.

#define C_CONST 6
#define D_CONST 128

__global__ __launch_bounds__(256) void eges_kernel(
    const int* __restrict__ central,       // [B]
    const int* __restrict__ side0,         // [B]
    const int* __restrict__ side1,         // [B,5]
    const int* __restrict__ ctx_items,     // [B,C]
    const float* __restrict__ W_item_in,   // [N,D]
    const float* __restrict__ W_item_out,  // [N,D]
    const float* __restrict__ W_weights,   // [N,3]
    const float* __restrict__ W_side0,     // [V0,D]
    const float* __restrict__ W_side1,     // [V1,D]
    float* __restrict__ out,               // [B,C]
    int B)
{
    const int wave = threadIdx.x >> 6;        // 4 waves/block
    const int lane = threadIdx.x & 63;
    const int half = lane >> 5;               // which of the 2 rows this wave owns
    const int l    = lane & 31;
    const int b = blockIdx.x * 8 + wave * 2 + half;
    if (b >= B) return;

    const int d = l * 4;                      // each lane owns 4 consecutive floats

    // ---- load all indices first ----
    const int ci  = central[b];
    const int s0i = side0[b];

    int s1idx[5];
    #pragma unroll
    for (int j = 0; j < 5; ++j) s1idx[j] = side1[b * 5 + j];

    const int2 c01 = *(const int2*)&ctx_items[b * 6 + 0];
    const int2 c23 = *(const int2*)&ctx_items[b * 6 + 2];
    const int2 c45 = *(const int2*)&ctx_items[b * 6 + 4];
    const int cidx[6] = { c01.x, c01.y, c23.x, c23.y, c45.x, c45.y };

    // ---- issue all row gathers (13 per row, 1KB per wave instruction) ----
    const float4 item = *(const float4*)&W_item_in[(long long)ci  * D_CONST + d];
    const float4 s0v  = *(const float4*)&W_side0 [(long long)s0i * D_CONST + d];

    float4 sacc = make_float4(0.f, 0.f, 0.f, 0.f);
    #pragma unroll
    for (int j = 0; j < 5; ++j) {
        float4 t = *(const float4*)&W_side1[(long long)s1idx[j] * D_CONST + d];
        sacc.x += t.x; sacc.y += t.y; sacc.z += t.z; sacc.w += t.w;
    }

    float4 o[6];
    #pragma unroll
    for (int c = 0; c < 6; ++c)
        o[c] = *(const float4*)&W_item_out[(long long)cidx[c] * D_CONST + d];

    // ---- softmax over the 3 mixing weights (uniform within half-wave) ----
    const float* wp = &W_weights[(long long)ci * 3];
    float w0 = wp[0], w1 = wp[1], w2 = wp[2];
    const float m = fmaxf(w0, fmaxf(w1, w2));
    const float e0 = __expf(w0 - m), e1 = __expf(w1 - m), e2 = __expf(w2 - m);
    const float inv = 1.0f / (e0 + e1 + e2);
    w0 = e0 * inv; w1 = e1 * inv; w2 = e2 * inv;

    float4 h;
    h.x = w0 * item.x + w1 * s0v.x + w2 * (sacc.x * 0.2f);
    h.y = w0 * item.y + w1 * s0v.y + w2 * (sacc.y * 0.2f);
    h.z = w0 * item.z + w1 * s0v.z + w2 * (sacc.z * 0.2f);
    h.w = w0 * item.w + w1 * s0v.w + w2 * (sacc.w * 0.2f);

    // ---- 6 dot products, 5-step butterfly within the 32-lane half ----
    #pragma unroll
    for (int c = 0; c < 6; ++c) {
        float p = h.x * o[c].x + h.y * o[c].y + h.z * o[c].z + h.w * o[c].w;
        #pragma unroll
        for (int off = 16; off >= 1; off >>= 1)
            p += __shfl_xor(p, off, 64);   // xor < 32 stays within the half-wave
        if (l == 0)
            out[b * 6 + c] = 1.0f / (1.0f + __expf(-p));
    }
}

extern "C" void kernel_launch(void* const* d_in, const int* in_sizes, int n_in,
                              void* d_out, int out_size, void* d_ws, size_t ws_size,
                              hipStream_t stream) {
    const int*   central    = (const int*)d_in[0];
    const int*   side0      = (const int*)d_in[1];
    const int*   side1      = (const int*)d_in[2];
    const int*   ctx_items  = (const int*)d_in[3];
    const float* W_item_in  = (const float*)d_in[4];
    const float* W_item_out = (const float*)d_in[5];
    const float* W_weights  = (const float*)d_in[6];
    const float* W_side0    = (const float*)d_in[7];
    const float* W_side1    = (const float*)d_in[8];
    float* out = (float*)d_out;

    const int B = in_sizes[0];              // 16384
    const int blocks = (B + 7) / 8;         // 8 rows per 256-thread block (2 per wave)

    eges_kernel<<<blocks, 256, 0, stream>>>(
        central, side0, side1, ctx_items,
        W_item_in, W_item_out, W_weights, W_side0, W_side1,
        out, B);
}

// Round 3
// 22.067 us; speedup vs baseline: 1.1586x; 1.0230x over previous
//
#include <hip/hip_runtime.h>
#include <math.h>

// EGES: hidden = softmax(W_weights[central]) . {item_emb, side0, mean(side1)}
//       out[b,c] = sigmoid(dot(hidden[b], W_item_out[context[b,c]]))
// B=16384, C=6, D=128.
// Layout: one wave handles FOUR rows (lane>>4 picks the row); each 16-lane
// quarter covers one 512B embedding row with float8 (2x float4) loads.
// Every gather instruction moves 1KB; 26 gathers per wave are issued
// back-to-back for max memory-level parallelism. Reduction: 4-step shfl_xor
// within the 16-lane group reduces all 4 rows at once.

#define D_CONST 128

__global__ __launch_bounds__(256, 4) void eges_kernel(
    const int* __restrict__ central,       // [B]
    const int* __restrict__ side0,         // [B]
    const int* __restrict__ side1,         // [B,5]
    const int* __restrict__ ctx_items,     // [B,C]
    const float* __restrict__ W_item_in,   // [N,D]
    const float* __restrict__ W_item_out,  // [N,D]
    const float* __restrict__ W_weights,   // [N,3]
    const float* __restrict__ W_side0,     // [V0,D]
    const float* __restrict__ W_side1,     // [V1,D]
    float* __restrict__ out,               // [B,C]
    int B)
{
    const int wave = threadIdx.x >> 6;        // 4 waves/block
    const int lane = threadIdx.x & 63;
    const int q    = lane >> 4;               // which of the 4 rows this wave owns
    const int l    = lane & 15;
    const int b = blockIdx.x * 16 + wave * 4 + q;
    if (b >= B) return;

    const int d = l * 8;                      // each lane owns 8 consecutive floats

    // ---- indices ----
    const int ci  = central[b];
    const int s0i = side0[b];

    int s1idx[5];
    #pragma unroll
    for (int j = 0; j < 5; ++j) s1idx[j] = side1[b * 5 + j];

    const int2 c01 = *(const int2*)&ctx_items[b * 6 + 0];
    const int2 c23 = *(const int2*)&ctx_items[b * 6 + 2];
    const int2 c45 = *(const int2*)&ctx_items[b * 6 + 4];
    const int cidx[6] = { c01.x, c01.y, c23.x, c23.y, c45.x, c45.y };

    // ---- row gathers: 1KB per wave instruction, all independent ----
    const float* ip = &W_item_in[(long long)ci  * D_CONST + d];
    const float4 itemA = *(const float4*)ip;
    const float4 itemB = *(const float4*)(ip + 4);

    const float* sp = &W_side0[(long long)s0i * D_CONST + d];
    const float4 s0A = *(const float4*)sp;
    const float4 s0B = *(const float4*)(sp + 4);

    float4 saA = make_float4(0.f,0.f,0.f,0.f), saB = make_float4(0.f,0.f,0.f,0.f);
    #pragma unroll
    for (int j = 0; j < 5; ++j) {
        const float* tp = &W_side1[(long long)s1idx[j] * D_CONST + d];
        float4 tA = *(const float4*)tp;
        float4 tB = *(const float4*)(tp + 4);
        saA.x += tA.x; saA.y += tA.y; saA.z += tA.z; saA.w += tA.w;
        saB.x += tB.x; saB.y += tB.y; saB.z += tB.z; saB.w += tB.w;
    }

    float4 oA[6], oB[6];
    #pragma unroll
    for (int c = 0; c < 6; ++c) {
        const float* op = &W_item_out[(long long)cidx[c] * D_CONST + d];
        oA[c] = *(const float4*)op;
        oB[c] = *(const float4*)(op + 4);
    }

    // ---- softmax over the 3 mixing weights (uniform within quarter-wave) ----
    const float* wp = &W_weights[(long long)ci * 3];
    float w0 = wp[0], w1 = wp[1], w2 = wp[2];
    const float m = fmaxf(w0, fmaxf(w1, w2));
    const float e0 = __expf(w0 - m), e1 = __expf(w1 - m), e2 = __expf(w2 - m);
    const float inv = 1.0f / (e0 + e1 + e2);
    w0 = e0 * inv; w1 = e1 * inv; w2 = e2 * inv;
    const float w2s = w2 * 0.2f;

    float4 hA, hB;
    hA.x = w0*itemA.x + w1*s0A.x + w2s*saA.x;
    hA.y = w0*itemA.y + w1*s0A.y + w2s*saA.y;
    hA.z = w0*itemA.z + w1*s0A.z + w2s*saA.z;
    hA.w = w0*itemA.w + w1*s0A.w + w2s*saA.w;
    hB.x = w0*itemB.x + w1*s0B.x + w2s*saB.x;
    hB.y = w0*itemB.y + w1*s0B.y + w2s*saB.y;
    hB.z = w0*itemB.z + w1*s0B.z + w2s*saB.z;
    hB.w = w0*itemB.w + w1*s0B.w + w2s*saB.w;

    // ---- 6 dot products; 4-step butterfly inside the 16-lane group
    //      reduces all four of the wave's rows simultaneously ----
    #pragma unroll
    for (int c = 0; c < 6; ++c) {
        float p = hA.x*oA[c].x + hA.y*oA[c].y + hA.z*oA[c].z + hA.w*oA[c].w
                + hB.x*oB[c].x + hB.y*oB[c].y + hB.z*oB[c].z + hB.w*oB[c].w;
        #pragma unroll
        for (int off = 8; off >= 1; off >>= 1)
            p += __shfl_xor(p, off, 64);   // xor < 16 stays within the quarter
        if (l == 0)
            out[b * 6 + c] = 1.0f / (1.0f + __expf(-p));
    }
}

extern "C" void kernel_launch(void* const* d_in, const int* in_sizes, int n_in,
                              void* d_out, int out_size, void* d_ws, size_t ws_size,
                              hipStream_t stream) {
    const int*   central    = (const int*)d_in[0];
    const int*   side0      = (const int*)d_in[1];
    const int*   side1      = (const int*)d_in[2];
    const int*   ctx_items  = (const int*)d_in[3];
    const float* W_item_in  = (const float*)d_in[4];
    const float* W_item_out = (const float*)d_in[5];
    const float* W_weights  = (const float*)d_in[6];
    const float* W_side0    = (const float*)d_in[7];
    const float* W_side1    = (const float*)d_in[8];
    float* out = (float*)d_out;

    const int B = in_sizes[0];              // 16384
    const int blocks = (B + 15) / 16;       // 16 rows per 256-thread block (4 per wave)

    eges_kernel<<<blocks, 256, 0, stream>>>(
        central, side0, side1, ctx_items,
        W_item_in, W_item_out, W_weights, W_side0, W_side1,
        out, B);
}